// Round 1
// baseline (318.565 us; speedup 1.0000x reference)
//
#include <hip/hip_runtime.h>
#include <math.h>

#define HWDIM 256
#define CH 32
#define NB 8
#define TILE 16
#define NLOC (NB*HWDIM*HWDIM)   /* 524288 locations */
#define R_CLAMP 4.9517189f      /* artanh(0.9999) */
#define MAXN 0.9999f
#define BN_EPS 1e-5f
#define EPSF 1e-5f
#define GRIDC 512               /* persistent conv blocks */
#define TPB 4                   /* tiles per block (4*512 = 2048 tiles) */
#define OST 264                 /* out_kernel LDS row stride (floats) */

typedef __attribute__((ext_vector_type(8))) _Float16 half8;
typedef __attribute__((ext_vector_type(4))) _Float16 half4;
typedef __attribute__((ext_vector_type(4))) float floatx4;

__device__ __forceinline__ float artanh_fast(float n) {
    float t = fminf(n, 1.0f - 1e-5f);
    // artanh(t) = 0.5*ln((1+t)/(1-t)); v_log_f32-based, ~1e-6 rel err << fp16 path rounding
    return 0.5f * __logf(__fdividef(1.0f + t, 1.0f - t));
}

// pack both weight tensors to fp16: w[co][ci][3][3] -> wp[((o*4+g)*32+co)*8+j], ci=g*8+j
__global__ __launch_bounds__(256) void wprep_kernel(
    const float* __restrict__ w1, const float* __restrict__ w2,
    _Float16* __restrict__ wp1, _Float16* __restrict__ wp2)
{
    int idx = blockIdx.x * 256 + threadIdx.x;
    if (idx >= 2*CH*CH*9) return;
    int s = idx >= CH*CH*9;
    int id = idx - s*(CH*CH*9);
    const float* w = s ? w2 : w1;
    _Float16* wp = s ? wp2 : wp1;
    int j  = id & 7;
    int r  = id >> 3;
    int co = r & 31;
    int og = r >> 5;
    int g  = og & 3;
    int o  = og >> 2;
    int ci = g*8 + j;
    wp[id] = (_Float16)w[(co*CH + ci)*9 + o];
}

// STAGE 1: src = x fp32 NCHW, staging transform = logmap0
// STAGE 2: src = t1 fp16 channel-minor [N*H*W][32], transform = bn1+clampnorm+relu
// dst (both stages): fp16 channel-minor [N*H*W][32]
// Persistent-pipelined: each block owns TPB adjacent tiles of one image.
// Per tile: transform(regs->LDS); barrier; issue prefetch(next tile)->regs;
// MFMA+epilogue (loads in flight underneath); barrier.
template<int STAGE>
__global__ __launch_bounds__(512, 4) void conv_mfma_kernel(
    const void* __restrict__ srcv,
    const _Float16* __restrict__ wp,      // [9][4][32co][8ci] fp16
    const float* __restrict__ bias,
    const float* __restrict__ scsh,       // [2*CH] (STAGE 2)
    _Float16* __restrict__ dst,
    float* __restrict__ partials)         // [64][GRIDC] transposed
{
    __shared__ _Float16 ah[10368];        // [18y][4g][18x][8ci] = 20736 B
    __shared__ float red[8][64];

    const int tid = threadIdx.x;
    const int b   = blockIdx.x;
    // image index = b&7 so each XCD rasters one image; 4 tiles march in x (halo overlap L2-hot)
    const int bz  = b & 7;
    const int tb  = b >> 3;               // 0..63
    const int by  = tb >> 2;              // tile row (constant over j)
    const int bx0 = (tb & 3) * TPB;       // first tile col
    const int h0  = by*TILE - 1;

    const int lane = tid & 63, wave = tid >> 6;
    const int xx = lane & 15, q = lane >> 4;

    // staging assignment: one halo loc per thread (324 <= 512)
    const bool sact = (tid < 324);
    int sy = 0, sx = 0;
    if (sact) { sy = tid / 18; sx = tid - sy*18; }
    const int gh = h0 + sy;
    const bool rowok = sact && (gh >= 0) && (gh < HWDIM);

    float  pf[CH];      // STAGE 1 prefetch regs
    half8  praw[4];     // STAGE 2 prefetch regs
    bool   inb = false;

    // prefetch raw loc data for tile j into registers (issue only, no use)
    auto PREFETCH = [&](int j) {
        if (!sact) return;
        const int gw = bx0*TILE + j*TILE - 1 + sx;
        inb = rowok && (gw >= 0) && (gw < HWDIM);
        if (!inb) return;
        if (STAGE == 1) {
            const float* p = (const float*)srcv + ((size_t)bz*CH << 16) + gh*HWDIM + gw;
            #pragma unroll
            for (int c = 0; c < CH; c++) pf[c] = p[(size_t)c << 16];
        } else {
            const _Float16* p = (const _Float16*)srcv + (((size_t)bz << 16) + gh*HWDIM + gw)*CH;
            #pragma unroll
            for (int k = 0; k < 4; k++) praw[k] = *(const half8*)(p + 8*k);
        }
    };

    // transform prefetched regs -> fp16 A-tile in LDS
    auto TRANSFORM = [&]() {
        if (!sact) return;
        _Float16* base = ah + ((sy*4)*18 + sx)*8;
        if (!inb) {
            half8 z = {0,0,0,0,0,0,0,0};
            #pragma unroll
            for (int g = 0; g < 4; g++) *(half8*)(base + g*18*8) = z;
            return;
        }
        float v[CH]; float n2 = 0.f;
        if (STAGE == 1) {
            #pragma unroll
            for (int c = 0; c < CH; c++) { float t0 = pf[c]; v[c] = t0; n2 = fmaf(t0, t0, n2); }
            float n = fmaxf(sqrtf(n2), EPSF);
            float f = __fdividef(artanh_fast(n), n);
            #pragma unroll
            for (int c = 0; c < CH; c++) v[c] *= f;
        } else {
            #pragma unroll
            for (int c = 0; c < CH; c++) {
                float t0 = fmaf((float)praw[c>>3][c&7], scsh[c], scsh[CH + c]);
                v[c] = t0; n2 = fmaf(t0, t0, n2);
            }
            float n = sqrtf(n2);
            float f = (n > R_CLAMP) ? __fdividef(R_CLAMP, n) : 1.0f;
            #pragma unroll
            for (int c = 0; c < CH; c++) v[c] = fmaxf(v[c]*f, 0.0f);
        }
        #pragma unroll
        for (int g = 0; g < 4; g++) {
            half8 hv;
            #pragma unroll
            for (int j2 = 0; j2 < 8; j2++) hv[j2] = (_Float16)v[g*8 + j2];
            *(half8*)(base + g*18*8) = hv;
        }
    };

    float bs[8];
    #pragma unroll
    for (int r = 0; r < 4; r++) { bs[r] = bias[q*4+r]; bs[4+r] = bias[q*4+r+16]; }
    float sv[8], qv[8];
    #pragma unroll
    for (int k = 0; k < 8; k++) { sv[k] = 0.f; qv[k] = 0.f; }

    PREFETCH(0);

    #pragma unroll 1
    for (int j = 0; j < TPB; j++) {
        TRANSFORM();                       // waits on tile-j loads (vmcnt), writes LDS
        __syncthreads();
        if (j + 1 < TPB) PREFETCH(j + 1);  // loads fly under MFMA+epilogue below

        floatx4 acc[2][2];
        #pragma unroll
        for (int i = 0; i < 2; i++) {
            acc[i][0] = (floatx4){0.f,0.f,0.f,0.f};
            acc[i][1] = (floatx4){0.f,0.f,0.f,0.f};
        }

        // implicit GEMM, swapped operands: A = weights (m=co), B = acts (n=loc)
        // wave owns output rows y = wave*2 + i (i=0,1)
        __builtin_amdgcn_s_setprio(1);
        #pragma unroll
        for (int dx = 0; dx < 3; dx++) {
            half8 af[4];
            #pragma unroll
            for (int yy = 0; yy < 4; yy++)
                af[yy] = *(const half8*)(ah + (((wave*2+yy)*4 + q)*18 + xx + dx)*8);
            #pragma unroll
            for (int dy = 0; dy < 3; dy++) {
                const int o = dy*3 + dx;
                const _Float16* wb = wp + (size_t)((o*4 + q)*32)*8;
                half8 wf0 = *(const half8*)(wb + xx*8);          // co 0..15
                half8 wf1 = *(const half8*)(wb + (xx+16)*8);     // co 16..31
                #pragma unroll
                for (int i = 0; i < 2; i++) {
                    acc[i][0] = __builtin_amdgcn_mfma_f32_16x16x32_f16(wf0, af[i+dy], acc[i][0], 0,0,0);
                    acc[i][1] = __builtin_amdgcn_mfma_f32_16x16x32_f16(wf1, af[i+dy], acc[i][1], 0,0,0);
                }
            }
        }
        __builtin_amdgcn_s_setprio(0);

        // register epilogue: thread owns ch {q*4+r, q*4+r+16} of loc (y=wave*2+i, x=xx)
        _Float16* dp = dst + (((size_t)bz << 16) + (size_t)(by*TILE)*HWDIM + (bx0 + j)*TILE + xx)*CH + q*4;
        #pragma unroll
        for (int i = 0; i < 2; i++) {
            float n2 = 0.f;
            #pragma unroll
            for (int r = 0; r < 4; r++) {
                acc[i][0][r] += bs[r];
                acc[i][1][r] += bs[4+r];
                n2 = fmaf(acc[i][0][r], acc[i][0][r], n2);
                n2 = fmaf(acc[i][1][r], acc[i][1][r], n2);
            }
            n2 += __shfl_xor(n2, 16, 64);
            n2 += __shfl_xor(n2, 32, 64);
            float nn = sqrtf(n2);
            float f = (nn > R_CLAMP) ? __fdividef(R_CLAMP, nn) : 1.0f;
            half4 o0, o1;
            #pragma unroll
            for (int r = 0; r < 4; r++) {
                float a0 = acc[i][0][r] * f;
                float a1 = acc[i][1][r] * f;
                sv[r]   += a0; qv[r]   = fmaf(a0, a0, qv[r]);
                sv[4+r] += a1; qv[4+r] = fmaf(a1, a1, qv[4+r]);
                o0[r] = (_Float16)a0; o1[r] = (_Float16)a1;
            }
            _Float16* a = dp + (size_t)(wave*2 + i)*HWDIM*CH;
            *(half4*)(a)      = o0;
            *(half4*)(a + 16) = o1;
        }
        __syncthreads();                   // LDS safe to overwrite next iteration
    }

    // BN partials: accumulated over all TPB tiles, reduced once per block
    #pragma unroll
    for (int k = 0; k < 8; k++) {
        #pragma unroll
        for (int m = 1; m < 16; m <<= 1) {
            sv[k] += __shfl_xor(sv[k], m, 64);
            qv[k] += __shfl_xor(qv[k], m, 64);
        }
    }
    if (xx == 0) {
        #pragma unroll
        for (int r = 0; r < 4; r++) {
            red[wave][q*4+r]        = sv[r];
            red[wave][16 + q*4+r]   = sv[4+r];
            red[wave][32 + q*4+r]   = qv[r];
            red[wave][48 + q*4+r]   = qv[4+r];
        }
    }
    __syncthreads();
    if (tid < 64) {
        float s = 0.f;
        #pragma unroll
        for (int w = 0; w < 8; w++) s += red[w][tid];
        partials[(size_t)tid*GRIDC + b] = s;
    }
}

__global__ __launch_bounds__(256) void finalize_kernel(
    const float* __restrict__ partials,
    const float* __restrict__ g, const float* __restrict__ beta,
    float* __restrict__ scsh)
{
    __shared__ float ss[256], sq[256];
    const int c = blockIdx.x;
    const int tid = threadIdx.x;
    float s = 0.f, q = 0.f;
    for (int b = tid; b < GRIDC; b += 256) {
        s += partials[(size_t)c*GRIDC + b];
        q += partials[(size_t)(CH + c)*GRIDC + b];
    }
    ss[tid] = s; sq[tid] = q;
    __syncthreads();
    for (int st = 128; st > 0; st >>= 1) {
        if (tid < st) { ss[tid] += ss[tid+st]; sq[tid] += sq[tid+st]; }
        __syncthreads();
    }
    if (tid == 0) {
        const float NS = (float)NLOC;
        float mean = ss[0] / NS;
        float var = fmaxf(sq[0] / NS - mean*mean, 0.0f);
        float sc = g[c] / sqrtf(var + BN_EPS);
        scsh[c] = sc;
        scsh[CH + c] = beta[c] - mean*sc;
    }
}

// read t4 fp16 channel-minor; bn2+clampnorm+relu+expmap0+project; write fp32 NCHW
__global__ __launch_bounds__(256) void out_kernel(
    const _Float16* __restrict__ t4c, const float* __restrict__ scsh,
    float* __restrict__ out)
{
    __shared__ float outb[16*OST];
    const int w = threadIdx.x;
    const int h = blockIdx.x, n = blockIdx.y;
    const _Float16* p = t4c + (((size_t)n << 16) + (size_t)h*HWDIM + w)*CH;
    half8 raw[4];
    #pragma unroll
    for (int k = 0; k < 4; k++) raw[k] = *(const half8*)(p + 8*k);
    float u[CH]; float n2 = 0.f;
    #pragma unroll
    for (int c = 0; c < CH; c++) {
        float t = fmaf((float)raw[c>>3][c&7], scsh[c], scsh[CH+c]);
        u[c] = t; n2 = fmaf(t, t, n2);
    }
    float nn = sqrtf(n2);
    float f = (nn > R_CLAMP) ? (R_CLAMP/nn) : 1.0f;
    float r2 = 0.f;
    #pragma unroll
    for (int c = 0; c < CH; c++) { float r = fmaxf(u[c]*f, 0.0f); u[c] = r; r2 = fmaf(r, r, r2); }
    float rn = fmaxf(sqrtf(r2), EPSF);
    float s = fminf(tanhf(rn), MAXN) / rn;
    #pragma unroll
    for (int c = 0; c < CH; c++) u[c] *= s;

    #pragma unroll
    for (int hf = 0; hf < 2; hf++) {
        if (hf) __syncthreads();
        #pragma unroll
        for (int c = 0; c < 16; c++) outb[c*OST + w] = u[hf*16 + c];
        __syncthreads();
        int co = threadIdx.x >> 4, seg = threadIdx.x & 15;
        const float* row = outb + co*OST + seg*16;
        float* gp = out + ((size_t)(n*CH + hf*16 + co) << 16) + (size_t)h*HWDIM + seg*16;
        #pragma unroll
        for (int k = 0; k < 4; k++) *(floatx4*)(gp + 4*k) = *(const floatx4*)(row + 4*k);
    }
}

extern "C" void kernel_launch(void* const* d_in, const int* in_sizes, int n_in,
                              void* d_out, int out_size, void* d_ws, size_t ws_size,
                              hipStream_t stream)
{
    const float* x   = (const float*)d_in[0];
    const float* w1  = (const float*)d_in[1];
    const float* b1  = (const float*)d_in[2];
    const float* g1  = (const float*)d_in[3];
    const float* be1 = (const float*)d_in[4];
    const float* w2  = (const float*)d_in[5];
    const float* b2  = (const float*)d_in[6];
    const float* g2  = (const float*)d_in[7];
    const float* be2 = (const float*)d_in[8];
    float* outf = (float*)d_out;

    char* ws = (char*)d_ws;
    _Float16* wp1   = (_Float16*)ws;                     // 9216 halves
    _Float16* wp2   = wp1 + 9216;                        // 9216 halves -> 36864 B
    float* partials = (float*)(ws + 36864);              // [64][GRIDC] floats
    float* scsh1    = (float*)(ws + 36864 + 524288);     // 64
    float* scsh2    = scsh1 + 64;                        // 64
    _Float16* t1c   = (_Float16*)(scsh2 + 64);           // 16.7M halves (32 MB)
    _Float16* t4c   = t1c + (size_t)NLOC*CH;             // 16.7M halves (32 MB)

    wprep_kernel<<<72, 256, 0, stream>>>(w1, w2, wp1, wp2);

    conv_mfma_kernel<1><<<GRIDC, 512, 0, stream>>>(x, wp1, b1, scsh1, t1c, partials);
    finalize_kernel<<<32, 256, 0, stream>>>(partials, g1, be1, scsh1);
    conv_mfma_kernel<2><<<GRIDC, 512, 0, stream>>>(t1c, wp2, b2, scsh1, t4c, partials);
    finalize_kernel<<<32, 256, 0, stream>>>(partials, g2, be2, scsh2);
    out_kernel<<<dim3(HWDIM, NB), 256, 0, stream>>>(t4c, scsh2, outf);
}

// Round 2
// 290.044 us; speedup vs baseline: 1.0983x; 1.0983x over previous
//
#include <hip/hip_runtime.h>
#include <math.h>

#define HWDIM 256
#define CH 32
#define NB 8
#define TILE 16
#define NLOC (NB*HWDIM*HWDIM)   /* 524288 locations */
#define R_CLAMP 4.9517189f      /* artanh(0.9999) */
#define MAXN 0.9999f
#define BN_EPS 1e-5f
#define EPSF 1e-5f
#define TPB 2                   /* tiles per conv block */
#define GRIDC 1024              /* conv blocks = 2048 tiles / TPB */
#define OST 264                 /* out_kernel LDS row stride (floats) */

typedef __attribute__((ext_vector_type(8))) _Float16 half8;
typedef __attribute__((ext_vector_type(4))) _Float16 half4;
typedef __attribute__((ext_vector_type(4))) float floatx4;

__device__ __forceinline__ float artanh_fast(float n) {
    float t = fminf(n, 1.0f - 1e-5f);
    // artanh(t) = 0.5*ln((1+t)/(1-t)); one v_log + fast divide; ~1e-6 rel err << fp16 path
    return 0.5f * __logf(__fdividef(1.0f + t, 1.0f - t));
}

// pack both weight tensors to fp16: w[co][ci][3][3] -> wp[((o*4+g)*32+co)*8+j], ci=g*8+j
__global__ __launch_bounds__(256) void wprep_kernel(
    const float* __restrict__ w1, const float* __restrict__ w2,
    _Float16* __restrict__ wp1, _Float16* __restrict__ wp2)
{
    int idx = blockIdx.x * 256 + threadIdx.x;
    if (idx >= 2*CH*CH*9) return;
    int s = idx >= CH*CH*9;
    int id = idx - s*(CH*CH*9);
    const float* w = s ? w2 : w1;
    _Float16* wp = s ? wp2 : wp1;
    int j  = id & 7;
    int r  = id >> 3;
    int co = r & 31;
    int og = r >> 5;
    int g  = og & 3;
    int o  = og >> 2;
    int ci = g*8 + j;
    wp[id] = (_Float16)w[(co*CH + ci)*9 + o];
}

// streaming logmap0: x fp32 NCHW (coalesced per-channel row reads) -> fp16 channel-minor
__global__ __launch_bounds__(256) void pre_kernel(
    const float* __restrict__ x, _Float16* __restrict__ t0c)
{
    const int w = threadIdx.x;
    const int h = blockIdx.x, n = blockIdx.y;
    const float* p = x + ((size_t)(n*CH) << 16) + (size_t)h*HWDIM + w;
    float v[CH]; float n2 = 0.f;
    #pragma unroll
    for (int c = 0; c < CH; c++) { float t = p[(size_t)c << 16]; v[c] = t; n2 = fmaf(t, t, n2); }
    float nn = fmaxf(sqrtf(n2), EPSF);
    float f = __fdividef(artanh_fast(nn), nn);
    _Float16* dp = t0c + (((size_t)n << 16) + (size_t)h*HWDIM + w)*CH;
    #pragma unroll
    for (int g = 0; g < 4; g++) {
        half8 hv;
        #pragma unroll
        for (int j = 0; j < 8; j++) hv[j] = (_Float16)(v[g*8 + j] * f);
        *(half8*)(dp + g*8) = hv;
    }
}

// transform prefetched regs -> fp16 A-tile row in LDS (layout [18y][4g][18x][8ci])
// STAGE 1: identity (src already = logmap0(x) fp16). STAGE 2: bn1 + clampnorm + relu.
template<int STAGE>
__device__ __forceinline__ void xform_store(const half8* pr, bool inb,
                                            _Float16* base, const float* __restrict__ scsh)
{
    if (!inb) {
        half8 z = {0,0,0,0,0,0,0,0};
        #pragma unroll
        for (int g = 0; g < 4; g++) *(half8*)(base + g*144) = z;
        return;
    }
    if (STAGE == 1) {
        #pragma unroll
        for (int g = 0; g < 4; g++) *(half8*)(base + g*144) = pr[g];
    } else {
        float v[CH]; float n2 = 0.f;
        #pragma unroll
        for (int c = 0; c < CH; c++) {
            float t0 = fmaf((float)pr[c>>3][c&7], scsh[c], scsh[CH + c]);
            v[c] = t0; n2 = fmaf(t0, t0, n2);
        }
        float n = sqrtf(n2);
        float f = (n > R_CLAMP) ? __fdividef(R_CLAMP, n) : 1.0f;
        #pragma unroll
        for (int g = 0; g < 4; g++) {
            half8 hv;
            #pragma unroll
            for (int j = 0; j < 8; j++) hv[j] = (_Float16)fmaxf(v[g*8 + j]*f, 0.0f);
            *(half8*)(base + g*144) = hv;
        }
    }
}

// Persistent-pipelined conv: TPB tiles marching in x per block.
// Per tile j: transform(regs->LDS); barrier; PREF(j+1) (loads fly under MFMA);
// MFMA + fused epilogue; barrier.
template<int STAGE>
__global__ __launch_bounds__(256, 4) void conv_mfma_kernel(
    const _Float16* __restrict__ src,     // fp16 channel-minor [N*H*W][32]
    const _Float16* __restrict__ wp,      // [9][4][32co][8ci] fp16
    const float* __restrict__ bias,
    const float* __restrict__ scsh,       // [2*CH] (STAGE 2)
    _Float16* __restrict__ dst,
    float* __restrict__ partials)         // [64][GRIDC] transposed
{
    __shared__ _Float16 ah[10368];        // [18y][4g][18x][8ci] = 20736 B
    __shared__ float red[4][64];

    const int tid = threadIdx.x;
    const int b   = blockIdx.x;           // 0..1023
    const int bz  = b & 7;                // image per XCD
    const int tb  = b >> 3;               // 0..127
    const int by  = tb >> 3;              // 0..15
    const int bx0 = (tb & 7) * TPB;       // 0,2,..,14
    const int h0  = by*TILE - 1;
    const int wbase = bx0*TILE - 1;

    // staging locs: loc0 = tid (all threads), loc1 = tid+256 (tid<68)
    const int sy0 = tid / 18, sx0 = tid - sy0*18;
    const int gh0 = h0 + sy0;
    const bool row0 = (gh0 >= 0) & (gh0 < HWDIM);
    const bool has1 = tid < 68;
    const int l1 = tid + 256;
    const int sy1 = l1 / 18, sx1 = l1 - sy1*18;
    const int gh1 = h0 + sy1;
    const bool row1 = has1 & (gh1 >= 0) & (gh1 < HWDIM);
    _Float16* const base0 = ah + ((sy0*4)*18 + sx0)*8;
    _Float16* const base1 = ah + ((sy1*4)*18 + sx1)*8;

    const int lane = tid & 63, wave = tid >> 6;
    const int xx = lane & 15, q = lane >> 4;

    half8 p0[4];                           // loc0 prefetch (16 VGPR, live across MFMA)
    bool in0 = false;

    // prefetch loc0 raw data for tile jj (issue only)
    #define PREF(jj) do {                                                              \
        int gw0 = wbase + (jj)*TILE + sx0;                                             \
        in0 = row0 & (gw0 >= 0) & (gw0 < HWDIM);                                       \
        if (in0) {                                                                     \
            const half8* p = (const half8*)(src + (((size_t)bz << 16) + gh0*HWDIM + gw0)*CH); \
            p0[0]=p[0]; p0[1]=p[1]; p0[2]=p[2]; p0[3]=p[3];                            \
        }                                                                              \
    } while (0)

    float bs[8];
    #pragma unroll
    for (int r = 0; r < 4; r++) { bs[r] = bias[q*4+r]; bs[4+r] = bias[q*4+r+16]; }
    float sv[8], qv[8];
    #pragma unroll
    for (int k = 0; k < 8; k++) { sv[k] = 0.f; qv[k] = 0.f; }

    PREF(0);

    #pragma unroll 1
    for (int j = 0; j < TPB; j++) {
        // loc1 (21% of halo): issue loads now, latency hides under loc0's transform
        half8 t1r[4]; bool tin1 = false;
        if (has1) {
            int gw1 = wbase + j*TILE + sx1;
            tin1 = row1 & (gw1 >= 0) & (gw1 < HWDIM);
            if (tin1) {
                const half8* p = (const half8*)(src + (((size_t)bz << 16) + gh1*HWDIM + gw1)*CH);
                t1r[0]=p[0]; t1r[1]=p[1]; t1r[2]=p[2]; t1r[3]=p[3];
            }
        }
        xform_store<STAGE>(p0, in0, base0, scsh);
        if (has1) xform_store<STAGE>(t1r, tin1, base1, scsh);
        __syncthreads();
        if (j + 1 < TPB) PREF(j + 1);      // next tile's loads fly under MFMA+epilogue

        floatx4 acc[4][2];
        #pragma unroll
        for (int i = 0; i < 4; i++) {
            acc[i][0] = (floatx4){0.f,0.f,0.f,0.f};
            acc[i][1] = (floatx4){0.f,0.f,0.f,0.f};
        }

        // implicit GEMM, swapped operands: A = weights (m=co), B = acts (n=loc)
        __builtin_amdgcn_s_setprio(1);
        #pragma unroll
        for (int dx = 0; dx < 3; dx++) {
            half8 af[6];
            #pragma unroll
            for (int yy = 0; yy < 6; yy++)
                af[yy] = *(const half8*)(ah + (((wave*4+yy)*4 + q)*18 + xx + dx)*8);
            #pragma unroll
            for (int dy = 0; dy < 3; dy++) {
                const int o = dy*3 + dx;
                const _Float16* wb = wp + (size_t)((o*4 + q)*32)*8;
                half8 wf0 = *(const half8*)(wb + xx*8);          // co 0..15
                half8 wf1 = *(const half8*)(wb + (xx+16)*8);     // co 16..31
                #pragma unroll
                for (int i = 0; i < 4; i++) {
                    acc[i][0] = __builtin_amdgcn_mfma_f32_16x16x32_f16(wf0, af[i+dy], acc[i][0], 0,0,0);
                    acc[i][1] = __builtin_amdgcn_mfma_f32_16x16x32_f16(wf1, af[i+dy], acc[i][1], 0,0,0);
                }
            }
        }
        __builtin_amdgcn_s_setprio(0);

        // register epilogue: thread owns ch {q*4+r, q*4+r+16} of loc (y=wave*4+i, x=xx)
        _Float16* dp = dst + (((size_t)bz << 16) + (size_t)(by*TILE)*HWDIM + (bx0 + j)*TILE + xx)*CH + q*4;
        #pragma unroll
        for (int i = 0; i < 4; i++) {
            float n2 = 0.f;
            #pragma unroll
            for (int r = 0; r < 4; r++) {
                acc[i][0][r] += bs[r];
                acc[i][1][r] += bs[4+r];
                n2 = fmaf(acc[i][0][r], acc[i][0][r], n2);
                n2 = fmaf(acc[i][1][r], acc[i][1][r], n2);
            }
            n2 += __shfl_xor(n2, 16, 64);
            n2 += __shfl_xor(n2, 32, 64);
            float nn = sqrtf(n2);
            float f = (nn > R_CLAMP) ? __fdividef(R_CLAMP, nn) : 1.0f;
            half4 o0, o1;
            #pragma unroll
            for (int r = 0; r < 4; r++) {
                float a0 = acc[i][0][r] * f;
                float a1 = acc[i][1][r] * f;
                sv[r]   += a0; qv[r]   = fmaf(a0, a0, qv[r]);
                sv[4+r] += a1; qv[4+r] = fmaf(a1, a1, qv[4+r]);
                o0[r] = (_Float16)a0; o1[r] = (_Float16)a1;
            }
            _Float16* a = dp + (size_t)(wave*4 + i)*HWDIM*CH;
            *(half4*)(a)      = o0;
            *(half4*)(a + 16) = o1;
        }
        __syncthreads();                   // LDS safe to overwrite next iteration
    }

    // BN partials accumulated over TPB tiles, reduced once per block
    #pragma unroll
    for (int k = 0; k < 8; k++) {
        #pragma unroll
        for (int m = 1; m < 16; m <<= 1) {
            sv[k] += __shfl_xor(sv[k], m, 64);
            qv[k] += __shfl_xor(qv[k], m, 64);
        }
    }
    if (xx == 0) {
        #pragma unroll
        for (int r = 0; r < 4; r++) {
            red[wave][q*4+r]        = sv[r];
            red[wave][16 + q*4+r]   = sv[4+r];
            red[wave][32 + q*4+r]   = qv[r];
            red[wave][48 + q*4+r]   = qv[4+r];
        }
    }
    __syncthreads();
    if (tid < 64) {
        float s = red[0][tid] + red[1][tid] + red[2][tid] + red[3][tid];
        partials[(size_t)tid*GRIDC + b] = s;
    }
    #undef PREF
}

__global__ __launch_bounds__(256) void finalize_kernel(
    const float* __restrict__ partials,
    const float* __restrict__ g, const float* __restrict__ beta,
    float* __restrict__ scsh)
{
    __shared__ float ss[256], sq[256];
    const int c = blockIdx.x;
    const int tid = threadIdx.x;
    float s = 0.f, q = 0.f;
    for (int b = tid; b < GRIDC; b += 256) {
        s += partials[(size_t)c*GRIDC + b];
        q += partials[(size_t)(CH + c)*GRIDC + b];
    }
    ss[tid] = s; sq[tid] = q;
    __syncthreads();
    for (int st = 128; st > 0; st >>= 1) {
        if (tid < st) { ss[tid] += ss[tid+st]; sq[tid] += sq[tid+st]; }
        __syncthreads();
    }
    if (tid == 0) {
        const float NS = (float)NLOC;
        float mean = ss[0] / NS;
        float var = fmaxf(sq[0] / NS - mean*mean, 0.0f);
        float sc = g[c] / sqrtf(var + BN_EPS);
        scsh[c] = sc;
        scsh[CH + c] = beta[c] - mean*sc;
    }
}

// read t4 fp16 channel-minor; bn2+clampnorm+relu+expmap0+project; write fp32 NCHW
__global__ __launch_bounds__(256) void out_kernel(
    const _Float16* __restrict__ t4c, const float* __restrict__ scsh,
    float* __restrict__ out)
{
    __shared__ float outb[16*OST];
    const int w = threadIdx.x;
    const int h = blockIdx.x, n = blockIdx.y;
    const _Float16* p = t4c + (((size_t)n << 16) + (size_t)h*HWDIM + w)*CH;
    half8 raw[4];
    #pragma unroll
    for (int k = 0; k < 4; k++) raw[k] = *(const half8*)(p + 8*k);
    float u[CH]; float n2 = 0.f;
    #pragma unroll
    for (int c = 0; c < CH; c++) {
        float t = fmaf((float)raw[c>>3][c&7], scsh[c], scsh[CH+c]);
        u[c] = t; n2 = fmaf(t, t, n2);
    }
    float nn = sqrtf(n2);
    float f = (nn > R_CLAMP) ? __fdividef(R_CLAMP, nn) : 1.0f;
    float r2 = 0.f;
    #pragma unroll
    for (int c = 0; c < CH; c++) { float r = fmaxf(u[c]*f, 0.0f); u[c] = r; r2 = fmaf(r, r, r2); }
    float rn = fmaxf(sqrtf(r2), EPSF);
    // tanh(rn) = (e^{2rn}-1)/(e^{2rn}+1); rn <= ~4.95 so e^{2rn} <= ~2e4, safe in fp32
    float a = __expf(2.0f * rn);
    float th = __fdividef(a - 1.0f, a + 1.0f);
    float s = __fdividef(fminf(th, MAXN), rn);
    #pragma unroll
    for (int c = 0; c < CH; c++) u[c] *= s;

    #pragma unroll
    for (int hf = 0; hf < 2; hf++) {
        if (hf) __syncthreads();
        #pragma unroll
        for (int c = 0; c < 16; c++) outb[c*OST + w] = u[hf*16 + c];
        __syncthreads();
        int co = threadIdx.x >> 4, seg = threadIdx.x & 15;
        const float* row = outb + co*OST + seg*16;
        float* gp = out + ((size_t)(n*CH + hf*16 + co) << 16) + (size_t)h*HWDIM + seg*16;
        #pragma unroll
        for (int k = 0; k < 4; k++) *(floatx4*)(gp + 4*k) = *(const floatx4*)(row + 4*k);
    }
}

extern "C" void kernel_launch(void* const* d_in, const int* in_sizes, int n_in,
                              void* d_out, int out_size, void* d_ws, size_t ws_size,
                              hipStream_t stream)
{
    const float* x   = (const float*)d_in[0];
    const float* w1  = (const float*)d_in[1];
    const float* b1  = (const float*)d_in[2];
    const float* g1  = (const float*)d_in[3];
    const float* be1 = (const float*)d_in[4];
    const float* w2  = (const float*)d_in[5];
    const float* b2  = (const float*)d_in[6];
    const float* g2  = (const float*)d_in[7];
    const float* be2 = (const float*)d_in[8];
    float* outf = (float*)d_out;

    char* ws = (char*)d_ws;
    _Float16* wp1   = (_Float16*)ws;                       // 9216 halves
    _Float16* wp2   = wp1 + 9216;                          // 9216 halves -> 36864 B
    float* partials = (float*)(ws + 36864);                // [64][1024] floats = 256 KB
    float* scsh1    = (float*)(ws + 36864 + 262144);       // 64
    float* scsh2    = scsh1 + 64;                          // 64
    _Float16* bufA  = (_Float16*)(scsh2 + 64);             // 32 MB: t0c, later t4c
    _Float16* bufB  = bufA + (size_t)NLOC*CH;              // 32 MB: t1c

    wprep_kernel<<<72, 256, 0, stream>>>(w1, w2, wp1, wp2);
    pre_kernel<<<dim3(HWDIM, NB), 256, 0, stream>>>(x, bufA);                   // t0c = logmap0(x)

    conv_mfma_kernel<1><<<GRIDC, 256, 0, stream>>>(bufA, wp1, b1, scsh1, bufB, partials);
    finalize_kernel<<<32, 256, 0, stream>>>(partials, g1, be1, scsh1);
    conv_mfma_kernel<2><<<GRIDC, 256, 0, stream>>>(bufB, wp2, b2, scsh1, bufA, partials);
    finalize_kernel<<<32, 256, 0, stream>>>(partials, g2, be2, scsh2);
    out_kernel<<<dim3(HWDIM, NB), 256, 0, stream>>>(bufA, scsh2, outf);
}

// Round 3
// 289.643 us; speedup vs baseline: 1.0999x; 1.0014x over previous
//
#include <hip/hip_runtime.h>
#include <math.h>

#define HWDIM 256
#define CH 32
#define NB 8
#define TILE 16
#define NLOC (NB*HWDIM*HWDIM)   /* 524288 locations */
#define R_CLAMP 4.9517189f      /* artanh(0.9999) */
#define MAXN 0.9999f
#define BN_EPS 1e-5f
#define EPSF 1e-5f
#define TPB 2                   /* tiles per conv block */
#define GRIDC 1024              /* conv blocks = 2048 tiles / TPB */
#define OST 264                 /* out_kernel LDS row stride (floats) */

typedef __attribute__((ext_vector_type(8))) _Float16 half8;
typedef __attribute__((ext_vector_type(4))) _Float16 half4;
typedef __attribute__((ext_vector_type(4))) float floatx4;

__device__ __forceinline__ float artanh_fast(float n) {
    float t = fminf(n, 1.0f - 1e-5f);
    // artanh(t) = 0.5*ln((1+t)/(1-t)); one v_log + fast divide; ~1e-6 rel err << fp16 path
    return 0.5f * __logf(__fdividef(1.0f + t, 1.0f - t));
}

// pack both weight tensors to fp16: w[co][ci][3][3] -> wp[((o*4+g)*32+co)*8+j], ci=g*8+j
__global__ __launch_bounds__(256) void wprep_kernel(
    const float* __restrict__ w1, const float* __restrict__ w2,
    _Float16* __restrict__ wp1, _Float16* __restrict__ wp2)
{
    int idx = blockIdx.x * 256 + threadIdx.x;
    if (idx >= 2*CH*CH*9) return;
    int s = idx >= CH*CH*9;
    int id = idx - s*(CH*CH*9);
    const float* w = s ? w2 : w1;
    _Float16* wp = s ? wp2 : wp1;
    int j  = id & 7;
    int r  = id >> 3;
    int co = r & 31;
    int og = r >> 5;
    int g  = og & 3;
    int o  = og >> 2;
    int ci = g*8 + j;
    wp[id] = (_Float16)w[(co*CH + ci)*9 + o];
}

// streaming logmap0: x fp32 NCHW (coalesced per-channel row reads) -> fp16 channel-minor
__global__ __launch_bounds__(256) void pre_kernel(
    const float* __restrict__ x, _Float16* __restrict__ t0c)
{
    const int w = threadIdx.x;
    const int h = blockIdx.x, n = blockIdx.y;
    const float* p = x + ((size_t)(n*CH) << 16) + (size_t)h*HWDIM + w;
    float v[CH]; float n2 = 0.f;
    #pragma unroll
    for (int c = 0; c < CH; c++) { float t = p[(size_t)c << 16]; v[c] = t; n2 = fmaf(t, t, n2); }
    float nn = fmaxf(sqrtf(n2), EPSF);
    float f = __fdividef(artanh_fast(nn), nn);
    _Float16* dp = t0c + (((size_t)n << 16) + (size_t)h*HWDIM + w)*CH;
    #pragma unroll
    for (int g = 0; g < 4; g++) {
        half8 hv;
        #pragma unroll
        for (int j = 0; j < 8; j++) hv[j] = (_Float16)(v[g*8 + j] * f);
        *(half8*)(dp + g*8) = hv;
    }
}

// transform prefetched regs -> fp16 A-tile row in LDS (layout [18y][4g][18x][8ci])
// STAGE 1: identity (src already = logmap0(x) fp16). STAGE 2: bn1 + clampnorm + relu.
template<int STAGE>
__device__ __forceinline__ void xform_store(const half8* pr, bool inb,
                                            _Float16* base, const float* __restrict__ scsh)
{
    if (!inb) {
        half8 z = {0,0,0,0,0,0,0,0};
        #pragma unroll
        for (int g = 0; g < 4; g++) *(half8*)(base + g*144) = z;
        return;
    }
    if (STAGE == 1) {
        #pragma unroll
        for (int g = 0; g < 4; g++) *(half8*)(base + g*144) = pr[g];
    } else {
        float v[CH]; float n2 = 0.f;
        #pragma unroll
        for (int c = 0; c < CH; c++) {
            float t0 = fmaf((float)pr[c>>3][c&7], scsh[c], scsh[CH + c]);
            v[c] = t0; n2 = fmaf(t0, t0, n2);
        }
        float n = sqrtf(n2);
        float f = (n > R_CLAMP) ? __fdividef(R_CLAMP, n) : 1.0f;
        #pragma unroll
        for (int g = 0; g < 4; g++) {
            half8 hv;
            #pragma unroll
            for (int j = 0; j < 8; j++) hv[j] = (_Float16)fmaxf(v[g*8 + j]*f, 0.0f);
            *(half8*)(base + g*144) = hv;
        }
    }
}

// Persistent-pipelined conv: TPB tiles marching in x per block.
// Per tile j: transform(regs->LDS); barrier; PREF(j+1) (loads fly under MFMA);
// MFMA + fused epilogue; barrier.
// waves_per_eu(4,4): hard 128-VGPR budget, 4 blocks/CU — stops the allocator from
// spilling down to 64 VGPR to chase 8 waves/EU (rounds 1-2 failure mode).
template<int STAGE>
__global__ __attribute__((amdgpu_waves_per_eu(4, 4))) __launch_bounds__(256)
void conv_mfma_kernel(
    const _Float16* __restrict__ src,     // fp16 channel-minor [N*H*W][32]
    const _Float16* __restrict__ wp,      // [9][4][32co][8ci] fp16
    const float* __restrict__ bias,
    const float* __restrict__ scsh,       // [2*CH] (STAGE 2)
    _Float16* __restrict__ dst,
    float* __restrict__ partials)         // [64][GRIDC] transposed
{
    __shared__ _Float16 ah[10368];        // [18y][4g][18x][8ci] = 20736 B
    __shared__ float red[4][64];

    const int tid = threadIdx.x;
    const int b   = blockIdx.x;           // 0..1023
    const int bz  = b & 7;                // image per XCD
    const int tb  = b >> 3;               // 0..127
    const int by  = tb >> 3;              // 0..15
    const int bx0 = (tb & 7) * TPB;       // 0,2,..,14
    const int h0  = by*TILE - 1;
    const int wbase = bx0*TILE - 1;

    // staging locs: loc0 = tid (all threads), loc1 = tid+256 (tid<68)
    const int sy0 = tid / 18, sx0 = tid - sy0*18;
    const int gh0 = h0 + sy0;
    const bool row0 = (gh0 >= 0) & (gh0 < HWDIM);
    const bool has1 = tid < 68;
    const int l1 = tid + 256;
    const int sy1 = l1 / 18, sx1 = l1 - sy1*18;
    const int gh1 = h0 + sy1;
    const bool row1 = has1 & (gh1 >= 0) & (gh1 < HWDIM);
    _Float16* const base0 = ah + ((sy0*4)*18 + sx0)*8;
    _Float16* const base1 = ah + ((sy1*4)*18 + sx1)*8;

    const int lane = tid & 63, wave = tid >> 6;
    const int xx = lane & 15, q = lane >> 4;

    half8 p0[4];                           // loc0 prefetch (16 VGPR, live across MFMA)
    bool in0 = false;

    // prefetch loc0 raw data for tile jj (issue only)
    #define PREF(jj) do {                                                              \
        int gw0 = wbase + (jj)*TILE + sx0;                                             \
        in0 = row0 & (gw0 >= 0) & (gw0 < HWDIM);                                       \
        if (in0) {                                                                     \
            const half8* p = (const half8*)(src + (((size_t)bz << 16) + gh0*HWDIM + gw0)*CH); \
            p0[0]=p[0]; p0[1]=p[1]; p0[2]=p[2]; p0[3]=p[3];                            \
        }                                                                              \
    } while (0)

    float bs[8];
    #pragma unroll
    for (int r = 0; r < 4; r++) { bs[r] = bias[q*4+r]; bs[4+r] = bias[q*4+r+16]; }
    float sv[8], qv[8];
    #pragma unroll
    for (int k = 0; k < 8; k++) { sv[k] = 0.f; qv[k] = 0.f; }

    PREF(0);

    #pragma unroll 1
    for (int j = 0; j < TPB; j++) {
        // loc1 (21% of halo): issue loads now, latency hides under loc0's transform
        half8 t1r[4]; bool tin1 = false;
        if (has1) {
            int gw1 = wbase + j*TILE + sx1;
            tin1 = row1 & (gw1 >= 0) & (gw1 < HWDIM);
            if (tin1) {
                const half8* p = (const half8*)(src + (((size_t)bz << 16) + gh1*HWDIM + gw1)*CH);
                t1r[0]=p[0]; t1r[1]=p[1]; t1r[2]=p[2]; t1r[3]=p[3];
            }
        }
        xform_store<STAGE>(p0, in0, base0, scsh);
        if (has1) xform_store<STAGE>(t1r, tin1, base1, scsh);
        __syncthreads();
        if (j + 1 < TPB) PREF(j + 1);      // next tile's loads fly under MFMA+epilogue

        floatx4 acc[4][2];
        #pragma unroll
        for (int i = 0; i < 4; i++) {
            acc[i][0] = (floatx4){0.f,0.f,0.f,0.f};
            acc[i][1] = (floatx4){0.f,0.f,0.f,0.f};
        }

        // implicit GEMM, swapped operands: A = weights (m=co), B = acts (n=loc)
        __builtin_amdgcn_s_setprio(1);
        #pragma unroll
        for (int dx = 0; dx < 3; dx++) {
            half8 af[6];
            #pragma unroll
            for (int yy = 0; yy < 6; yy++)
                af[yy] = *(const half8*)(ah + (((wave*4+yy)*4 + q)*18 + xx + dx)*8);
            #pragma unroll
            for (int dy = 0; dy < 3; dy++) {
                const int o = dy*3 + dx;
                const _Float16* wb = wp + (size_t)((o*4 + q)*32)*8;
                half8 wf0 = *(const half8*)(wb + xx*8);          // co 0..15
                half8 wf1 = *(const half8*)(wb + (xx+16)*8);     // co 16..31
                #pragma unroll
                for (int i = 0; i < 4; i++) {
                    acc[i][0] = __builtin_amdgcn_mfma_f32_16x16x32_f16(wf0, af[i+dy], acc[i][0], 0,0,0);
                    acc[i][1] = __builtin_amdgcn_mfma_f32_16x16x32_f16(wf1, af[i+dy], acc[i][1], 0,0,0);
                }
            }
        }
        __builtin_amdgcn_s_setprio(0);

        // register epilogue: thread owns ch {q*4+r, q*4+r+16} of loc (y=wave*4+i, x=xx)
        _Float16* dp = dst + (((size_t)bz << 16) + (size_t)(by*TILE)*HWDIM + (bx0 + j)*TILE + xx)*CH + q*4;
        #pragma unroll
        for (int i = 0; i < 4; i++) {
            float n2 = 0.f;
            #pragma unroll
            for (int r = 0; r < 4; r++) {
                acc[i][0][r] += bs[r];
                acc[i][1][r] += bs[4+r];
                n2 = fmaf(acc[i][0][r], acc[i][0][r], n2);
                n2 = fmaf(acc[i][1][r], acc[i][1][r], n2);
            }
            n2 += __shfl_xor(n2, 16, 64);
            n2 += __shfl_xor(n2, 32, 64);
            float nn = sqrtf(n2);
            float f = (nn > R_CLAMP) ? __fdividef(R_CLAMP, nn) : 1.0f;
            half4 o0, o1;
            #pragma unroll
            for (int r = 0; r < 4; r++) {
                float a0 = acc[i][0][r] * f;
                float a1 = acc[i][1][r] * f;
                sv[r]   += a0; qv[r]   = fmaf(a0, a0, qv[r]);
                sv[4+r] += a1; qv[4+r] = fmaf(a1, a1, qv[4+r]);
                o0[r] = (_Float16)a0; o1[r] = (_Float16)a1;
            }
            _Float16* a = dp + (size_t)(wave*4 + i)*HWDIM*CH;
            *(half4*)(a)      = o0;
            *(half4*)(a + 16) = o1;
        }
        __syncthreads();                   // LDS safe to overwrite next iteration
    }

    // BN partials accumulated over TPB tiles, reduced once per block
    #pragma unroll
    for (int k = 0; k < 8; k++) {
        #pragma unroll
        for (int m = 1; m < 16; m <<= 1) {
            sv[k] += __shfl_xor(sv[k], m, 64);
            qv[k] += __shfl_xor(qv[k], m, 64);
        }
    }
    if (xx == 0) {
        #pragma unroll
        for (int r = 0; r < 4; r++) {
            red[wave][q*4+r]        = sv[r];
            red[wave][16 + q*4+r]   = sv[4+r];
            red[wave][32 + q*4+r]   = qv[r];
            red[wave][48 + q*4+r]   = qv[4+r];
        }
    }
    __syncthreads();
    if (tid < 64) {
        float s = red[0][tid] + red[1][tid] + red[2][tid] + red[3][tid];
        partials[(size_t)tid*GRIDC + b] = s;
    }
    #undef PREF
}

__global__ __launch_bounds__(256) void finalize_kernel(
    const float* __restrict__ partials,
    const float* __restrict__ g, const float* __restrict__ beta,
    float* __restrict__ scsh)
{
    __shared__ float ss[256], sq[256];
    const int c = blockIdx.x;
    const int tid = threadIdx.x;
    float s = 0.f, q = 0.f;
    for (int b = tid; b < GRIDC; b += 256) {
        s += partials[(size_t)c*GRIDC + b];
        q += partials[(size_t)(CH + c)*GRIDC + b];
    }
    ss[tid] = s; sq[tid] = q;
    __syncthreads();
    for (int st = 128; st > 0; st >>= 1) {
        if (tid < st) { ss[tid] += ss[tid+st]; sq[tid] += sq[tid+st]; }
        __syncthreads();
    }
    if (tid == 0) {
        const float NS = (float)NLOC;
        float mean = ss[0] / NS;
        float var = fmaxf(sq[0] / NS - mean*mean, 0.0f);
        float sc = g[c] / sqrtf(var + BN_EPS);
        scsh[c] = sc;
        scsh[CH + c] = beta[c] - mean*sc;
    }
}

// read t4 fp16 channel-minor; bn2+clampnorm+relu+expmap0+project; write fp32 NCHW
__global__ __launch_bounds__(256) void out_kernel(
    const _Float16* __restrict__ t4c, const float* __restrict__ scsh,
    float* __restrict__ out)
{
    __shared__ float outb[16*OST];
    const int w = threadIdx.x;
    const int h = blockIdx.x, n = blockIdx.y;
    const _Float16* p = t4c + (((size_t)n << 16) + (size_t)h*HWDIM + w)*CH;
    half8 raw[4];
    #pragma unroll
    for (int k = 0; k < 4; k++) raw[k] = *(const half8*)(p + 8*k);
    float u[CH]; float n2 = 0.f;
    #pragma unroll
    for (int c = 0; c < CH; c++) {
        float t = fmaf((float)raw[c>>3][c&7], scsh[c], scsh[CH+c]);
        u[c] = t; n2 = fmaf(t, t, n2);
    }
    float nn = sqrtf(n2);
    float f = (nn > R_CLAMP) ? __fdividef(R_CLAMP, nn) : 1.0f;
    float r2 = 0.f;
    #pragma unroll
    for (int c = 0; c < CH; c++) { float r = fmaxf(u[c]*f, 0.0f); u[c] = r; r2 = fmaf(r, r, r2); }
    float rn = fmaxf(sqrtf(r2), EPSF);
    // tanh(rn) = (e^{2rn}-1)/(e^{2rn}+1); rn <= ~4.95 so e^{2rn} <= ~2e4, safe in fp32
    float a = __expf(2.0f * rn);
    float th = __fdividef(a - 1.0f, a + 1.0f);
    float s = __fdividef(fminf(th, MAXN), rn);
    #pragma unroll
    for (int c = 0; c < CH; c++) u[c] *= s;

    #pragma unroll
    for (int hf = 0; hf < 2; hf++) {
        if (hf) __syncthreads();
        #pragma unroll
        for (int c = 0; c < 16; c++) outb[c*OST + w] = u[hf*16 + c];
        __syncthreads();
        int co = threadIdx.x >> 4, seg = threadIdx.x & 15;
        const float* row = outb + co*OST + seg*16;
        float* gp = out + ((size_t)(n*CH + hf*16 + co) << 16) + (size_t)h*HWDIM + seg*16;
        #pragma unroll
        for (int k = 0; k < 4; k++) *(floatx4*)(gp + 4*k) = *(const floatx4*)(row + 4*k);
    }
}

extern "C" void kernel_launch(void* const* d_in, const int* in_sizes, int n_in,
                              void* d_out, int out_size, void* d_ws, size_t ws_size,
                              hipStream_t stream)
{
    const float* x   = (const float*)d_in[0];
    const float* w1  = (const float*)d_in[1];
    const float* b1  = (const float*)d_in[2];
    const float* g1  = (const float*)d_in[3];
    const float* be1 = (const float*)d_in[4];
    const float* w2  = (const float*)d_in[5];
    const float* b2  = (const float*)d_in[6];
    const float* g2  = (const float*)d_in[7];
    const float* be2 = (const float*)d_in[8];
    float* outf = (float*)d_out;

    char* ws = (char*)d_ws;
    _Float16* wp1   = (_Float16*)ws;                       // 9216 halves
    _Float16* wp2   = wp1 + 9216;                          // 9216 halves -> 36864 B
    float* partials = (float*)(ws + 36864);                // [64][1024] floats = 256 KB
    float* scsh1    = (float*)(ws + 36864 + 262144);       // 64
    float* scsh2    = scsh1 + 64;                          // 64
    _Float16* bufA  = (_Float16*)(scsh2 + 64);             // 32 MB: t0c, later t4c
    _Float16* bufB  = bufA + (size_t)NLOC*CH;              // 32 MB: t1c

    wprep_kernel<<<72, 256, 0, stream>>>(w1, w2, wp1, wp2);
    pre_kernel<<<dim3(HWDIM, NB), 256, 0, stream>>>(x, bufA);                   // t0c = logmap0(x)

    conv_mfma_kernel<1><<<GRIDC, 256, 0, stream>>>(bufA, wp1, b1, scsh1, bufB, partials);
    finalize_kernel<<<32, 256, 0, stream>>>(partials, g1, be1, scsh1);
    conv_mfma_kernel<2><<<GRIDC, 256, 0, stream>>>(bufB, wp2, b2, scsh1, bufA, partials);
    finalize_kernel<<<32, 256, 0, stream>>>(partials, g2, be2, scsh2);
    out_kernel<<<dim3(HWDIM, NB), 256, 0, stream>>>(bufA, scsh2, outf);
}

// Round 5
// 204.977 us; speedup vs baseline: 1.5541x; 1.4130x over previous
//
#include <hip/hip_runtime.h>
#include <math.h>

#define HWDIM 256
#define CH 32
#define NB 8
#define TILE 16
#define NLOC (NB*HWDIM*HWDIM)   /* 524288 locations */
#define R_CLAMP 4.9517189f      /* artanh(0.9999) */
#define MAXN 0.9999f
#define BN_EPS 1e-5f
#define EPSF 1e-5f
#define TPB 2                   /* tiles per conv block */
#define GRIDC 1024              /* conv blocks = 2048 tiles / TPB; 4 per CU */
#define OST 264                 /* out_kernel LDS row stride (floats) */

typedef __attribute__((ext_vector_type(8))) _Float16 half8;
typedef __attribute__((ext_vector_type(4))) _Float16 half4;
typedef __attribute__((ext_vector_type(4))) float floatx4;

__device__ __forceinline__ float artanh_fast(float n) {
    float t = fminf(n, 1.0f - 1e-5f);
    // artanh(t) = 0.5*ln((1+t)/(1-t)); one v_log + fast divide; ~1e-6 rel err << fp16 path
    return 0.5f * __logf(__fdividef(1.0f + t, 1.0f - t));
}

// pack both weight tensors to fp16: w[co][ci][3][3] -> wp[((o*4+g)*32+co)*8+j], ci=g*8+j
__global__ __launch_bounds__(256) void wprep_kernel(
    const float* __restrict__ w1, const float* __restrict__ w2,
    _Float16* __restrict__ wp1, _Float16* __restrict__ wp2)
{
    int idx = blockIdx.x * 256 + threadIdx.x;
    if (idx >= 2*CH*CH*9) return;
    int s = idx >= CH*CH*9;
    int id = idx - s*(CH*CH*9);
    const float* w = s ? w2 : w1;
    _Float16* wp = s ? wp2 : wp1;
    int j  = id & 7;
    int r  = id >> 3;
    int co = r & 31;
    int og = r >> 5;
    int g  = og & 3;
    int o  = og >> 2;
    int ci = g*8 + j;
    wp[id] = (_Float16)w[(co*CH + ci)*9 + o];
}

// streaming logmap0: x fp32 NCHW (coalesced per-channel row reads) -> fp16 channel-minor
__global__ __launch_bounds__(256) void pre_kernel(
    const float* __restrict__ x, _Float16* __restrict__ t0c)
{
    const int w = threadIdx.x;
    const int h = blockIdx.x, n = blockIdx.y;
    const float* p = x + ((size_t)(n*CH) << 16) + (size_t)h*HWDIM + w;
    float v[CH]; float n2 = 0.f;
    #pragma unroll
    for (int c = 0; c < CH; c++) { float t = p[(size_t)c << 16]; v[c] = t; n2 = fmaf(t, t, n2); }
    float nn = fmaxf(sqrtf(n2), EPSF);
    float f = __fdividef(artanh_fast(nn), nn);
    _Float16* dp = t0c + (((size_t)n << 16) + (size_t)h*HWDIM + w)*CH;
    #pragma unroll
    for (int g = 0; g < 4; g++) {
        half8 hv;
        #pragma unroll
        for (int j = 0; j < 8; j++) hv[j] = (_Float16)(v[g*8 + j] * f);
        *(half8*)(dp + g*8) = hv;
    }
}

// transform raw regs -> fp16 A-tile row in LDS (layout [18y][4g][18x][8ci])
// STAGE 1: identity (src already = logmap0(x) fp16). STAGE 2: bn1 + clampnorm + relu.
template<int STAGE>
__device__ __forceinline__ void xform_store(const half8* pr, bool inb,
                                            _Float16* base, const float* __restrict__ scsh)
{
    if (!inb) {
        half8 z = {0,0,0,0,0,0,0,0};
        #pragma unroll
        for (int g = 0; g < 4; g++) *(half8*)(base + g*144) = z;
        return;
    }
    if (STAGE == 1) {
        #pragma unroll
        for (int g = 0; g < 4; g++) *(half8*)(base + g*144) = pr[g];
    } else {
        float v[CH]; float n2 = 0.f;
        #pragma unroll
        for (int c = 0; c < CH; c++) {
            float t0 = fmaf((float)pr[c>>3][c&7], scsh[c], scsh[CH + c]);
            v[c] = t0; n2 = fmaf(t0, t0, n2);
        }
        float n = sqrtf(n2);
        float f = (n > R_CLAMP) ? __fdividef(R_CLAMP, n) : 1.0f;
        #pragma unroll
        for (int g = 0; g < 4; g++) {
            half8 hv;
            #pragma unroll
            for (int j = 0; j < 8; j++) hv[j] = (_Float16)fmaxf(v[g*8 + j]*f, 0.0f);
            *(half8*)(base + g*144) = hv;
        }
    }
}

// Multi-tile conv: TPB tiles marching in x per block (1024 blocks, 4/CU, all resident;
// blocks drift out of phase across tiles -> inter-block latency hiding).
// No prefetch state lives across the MFMA phase (rounds 1-3 spill lesson):
// staging regs are loaded and consumed within the staging phase only.
template<int STAGE>
__global__ __launch_bounds__(256) void conv_mfma_kernel(
    const _Float16* __restrict__ src,     // fp16 channel-minor [N*H*W][32]
    const _Float16* __restrict__ wp,      // [9][4][32co][8ci] fp16
    const float* __restrict__ bias,
    const float* __restrict__ scsh,       // [2*CH] (STAGE 2)
    _Float16* __restrict__ dst,
    float* __restrict__ partials)         // [64][GRIDC] transposed
{
    __shared__ _Float16 ah[10368];        // [18y][4g][18x][8ci] = 20736 B
    __shared__ float red[4][64];

    const int tid = threadIdx.x;
    const int b   = blockIdx.x;           // 0..1023
    const int bz  = b & 7;                // image per XCD
    const int tb  = b >> 3;               // 0..127
    const int by  = tb >> 3;              // 0..15
    const int bx0 = (tb & 7) * TPB;       // 0,2,..,14
    const int h0  = by*TILE - 1;
    const int wbase = bx0*TILE - 1;

    // staging locs: loc0 = tid (all threads), loc1 = tid+256 (tid<68)
    const int sy0 = tid / 18, sx0 = tid - sy0*18;
    const int gh0 = h0 + sy0;
    const bool row0 = (gh0 >= 0) & (gh0 < HWDIM);
    const bool has1 = tid < 68;
    const int l1 = tid + 256;
    const int sy1 = l1 / 18, sx1 = l1 - sy1*18;
    const int gh1 = h0 + sy1;
    const bool row1 = has1 & (gh1 >= 0) & (gh1 < HWDIM);
    _Float16* const base0 = ah + ((sy0*4)*18 + sx0)*8;
    _Float16* const base1 = ah + ((sy1*4)*18 + sx1)*8;

    const int lane = tid & 63, wave = tid >> 6;
    const int xx = lane & 15, q = lane >> 4;

    float bs[8];
    #pragma unroll
    for (int r = 0; r < 4; r++) { bs[r] = bias[q*4+r]; bs[4+r] = bias[q*4+r+16]; }
    float sv[8], qv[8];
    #pragma unroll
    for (int k = 0; k < 8; k++) { sv[k] = 0.f; qv[k] = 0.f; }

    #pragma unroll 1
    for (int j = 0; j < TPB; j++) {
        // ---- staging: issue both locs' loads, then transform (regs transient) ----
        half8 r0[4]; bool in0;
        {
            int gw0 = wbase + j*TILE + sx0;
            in0 = row0 & (gw0 >= 0) & (gw0 < HWDIM);
            if (in0) {
                const half8* p = (const half8*)(src + (((size_t)bz << 16) + gh0*HWDIM + gw0)*CH);
                r0[0]=p[0]; r0[1]=p[1]; r0[2]=p[2]; r0[3]=p[3];
            }
        }
        half8 r1[4]; bool in1 = false;
        if (has1) {
            int gw1 = wbase + j*TILE + sx1;
            in1 = row1 & (gw1 >= 0) & (gw1 < HWDIM);
            if (in1) {
                const half8* p = (const half8*)(src + (((size_t)bz << 16) + gh1*HWDIM + gw1)*CH);
                r1[0]=p[0]; r1[1]=p[1]; r1[2]=p[2]; r1[3]=p[3];
            }
        }
        xform_store<STAGE>(r0, in0, base0, scsh);
        if (has1) xform_store<STAGE>(r1, in1, base1, scsh);
        __syncthreads();

        // ---- implicit GEMM, swapped operands: A = weights (m=co), B = acts (n=loc) ----
        floatx4 acc[4][2];
        #pragma unroll
        for (int i = 0; i < 4; i++) {
            acc[i][0] = (floatx4){0.f,0.f,0.f,0.f};
            acc[i][1] = (floatx4){0.f,0.f,0.f,0.f};
        }
        __builtin_amdgcn_s_setprio(1);
        #pragma unroll
        for (int dx = 0; dx < 3; dx++) {
            half8 af[6];
            #pragma unroll
            for (int yy = 0; yy < 6; yy++)
                af[yy] = *(const half8*)(ah + (((wave*4+yy)*4 + q)*18 + xx + dx)*8);
            #pragma unroll
            for (int dy = 0; dy < 3; dy++) {
                const int o = dy*3 + dx;
                const _Float16* wb = wp + (size_t)((o*4 + q)*32)*8;
                half8 wf0 = *(const half8*)(wb + xx*8);          // co 0..15
                half8 wf1 = *(const half8*)(wb + (xx+16)*8);     // co 16..31
                #pragma unroll
                for (int i = 0; i < 4; i++) {
                    acc[i][0] = __builtin_amdgcn_mfma_f32_16x16x32_f16(wf0, af[i+dy], acc[i][0], 0,0,0);
                    acc[i][1] = __builtin_amdgcn_mfma_f32_16x16x32_f16(wf1, af[i+dy], acc[i][1], 0,0,0);
                }
            }
        }
        __builtin_amdgcn_s_setprio(0);

        // ---- register epilogue: thread owns ch {q*4+r, q*4+r+16} of loc (y=wave*4+i, x=xx) ----
        _Float16* dp = dst + (((size_t)bz << 16) + (size_t)(by*TILE)*HWDIM + (bx0 + j)*TILE + xx)*CH + q*4;
        #pragma unroll
        for (int i = 0; i < 4; i++) {
            float n2 = 0.f;
            #pragma unroll
            for (int r = 0; r < 4; r++) {
                acc[i][0][r] += bs[r];
                acc[i][1][r] += bs[4+r];
                n2 = fmaf(acc[i][0][r], acc[i][0][r], n2);
                n2 = fmaf(acc[i][1][r], acc[i][1][r], n2);
            }
            n2 += __shfl_xor(n2, 16, 64);
            n2 += __shfl_xor(n2, 32, 64);
            float nn = sqrtf(n2);
            float f = (nn > R_CLAMP) ? __fdividef(R_CLAMP, nn) : 1.0f;
            half4 o0, o1;
            #pragma unroll
            for (int r = 0; r < 4; r++) {
                float a0 = acc[i][0][r] * f;
                float a1 = acc[i][1][r] * f;
                sv[r]   += a0; qv[r]   = fmaf(a0, a0, qv[r]);
                sv[4+r] += a1; qv[4+r] = fmaf(a1, a1, qv[4+r]);
                o0[r] = (_Float16)a0; o1[r] = (_Float16)a1;
            }
            _Float16* a = dp + (size_t)(wave*4 + i)*HWDIM*CH;
            *(half4*)(a)      = o0;
            *(half4*)(a + 16) = o1;
        }
        __syncthreads();                   // LDS safe to overwrite next iteration
    }

    // BN partials accumulated over TPB tiles, reduced once per block
    #pragma unroll
    for (int k = 0; k < 8; k++) {
        #pragma unroll
        for (int m = 1; m < 16; m <<= 1) {
            sv[k] += __shfl_xor(sv[k], m, 64);
            qv[k] += __shfl_xor(qv[k], m, 64);
        }
    }
    if (xx == 0) {
        #pragma unroll
        for (int r = 0; r < 4; r++) {
            red[wave][q*4+r]        = sv[r];
            red[wave][16 + q*4+r]   = sv[4+r];
            red[wave][32 + q*4+r]   = qv[r];
            red[wave][48 + q*4+r]   = qv[4+r];
        }
    }
    __syncthreads();
    if (tid < 64) {
        float s = red[0][tid] + red[1][tid] + red[2][tid] + red[3][tid];
        partials[(size_t)tid*GRIDC + b] = s;
    }
}

__global__ __launch_bounds__(256) void finalize_kernel(
    const float* __restrict__ partials,
    const float* __restrict__ g, const float* __restrict__ beta,
    float* __restrict__ scsh)
{
    __shared__ float ss[256], sq[256];
    const int c = blockIdx.x;
    const int tid = threadIdx.x;
    float s = 0.f, q = 0.f;
    for (int b = tid; b < GRIDC; b += 256) {
        s += partials[(size_t)c*GRIDC + b];
        q += partials[(size_t)(CH + c)*GRIDC + b];
    }
    ss[tid] = s; sq[tid] = q;
    __syncthreads();
    for (int st = 128; st > 0; st >>= 1) {
        if (tid < st) { ss[tid] += ss[tid+st]; sq[tid] += sq[tid+st]; }
        __syncthreads();
    }
    if (tid == 0) {
        const float NS = (float)NLOC;
        float mean = ss[0] / NS;
        float var = fmaxf(sq[0] / NS - mean*mean, 0.0f);
        float sc = g[c] / sqrtf(var + BN_EPS);
        scsh[c] = sc;
        scsh[CH + c] = beta[c] - mean*sc;
    }
}

// read t4 fp16 channel-minor; bn2+clampnorm+relu+expmap0+project; write fp32 NCHW
__global__ __launch_bounds__(256) void out_kernel(
    const _Float16* __restrict__ t4c, const float* __restrict__ scsh,
    float* __restrict__ out)
{
    __shared__ float outb[16*OST];
    const int w = threadIdx.x;
    const int h = blockIdx.x, n = blockIdx.y;
    const _Float16* p = t4c + (((size_t)n << 16) + (size_t)h*HWDIM + w)*CH;
    half8 raw[4];
    #pragma unroll
    for (int k = 0; k < 4; k++) raw[k] = *(const half8*)(p + 8*k);
    float u[CH]; float n2 = 0.f;
    #pragma unroll
    for (int c = 0; c < CH; c++) {
        float t = fmaf((float)raw[c>>3][c&7], scsh[c], scsh[CH+c]);
        u[c] = t; n2 = fmaf(t, t, n2);
    }
    float nn = sqrtf(n2);
    float f = (nn > R_CLAMP) ? __fdividef(R_CLAMP, nn) : 1.0f;
    float r2 = 0.f;
    #pragma unroll
    for (int c = 0; c < CH; c++) { float r = fmaxf(u[c]*f, 0.0f); u[c] = r; r2 = fmaf(r, r, r2); }
    float rn = fmaxf(sqrtf(r2), EPSF);
    // tanh(rn) = (e^{2rn}-1)/(e^{2rn}+1); rn <= ~4.95 so e^{2rn} <= ~2e4, safe in fp32
    float a = __expf(2.0f * rn);
    float th = __fdividef(a - 1.0f, a + 1.0f);
    float s = __fdividef(fminf(th, MAXN), rn);
    #pragma unroll
    for (int c = 0; c < CH; c++) u[c] *= s;

    #pragma unroll
    for (int hf = 0; hf < 2; hf++) {
        if (hf) __syncthreads();
        #pragma unroll
        for (int c = 0; c < 16; c++) outb[c*OST + w] = u[hf*16 + c];
        __syncthreads();
        int co = threadIdx.x >> 4, seg = threadIdx.x & 15;
        const float* row = outb + co*OST + seg*16;
        float* gp = out + ((size_t)(n*CH + hf*16 + co) << 16) + (size_t)h*HWDIM + seg*16;
        #pragma unroll
        for (int k = 0; k < 4; k++) *(floatx4*)(gp + 4*k) = *(const floatx4*)(row + 4*k);
    }
}

extern "C" void kernel_launch(void* const* d_in, const int* in_sizes, int n_in,
                              void* d_out, int out_size, void* d_ws, size_t ws_size,
                              hipStream_t stream)
{
    const float* x   = (const float*)d_in[0];
    const float* w1  = (const float*)d_in[1];
    const float* b1  = (const float*)d_in[2];
    const float* g1  = (const float*)d_in[3];
    const float* be1 = (const float*)d_in[4];
    const float* w2  = (const float*)d_in[5];
    const float* b2  = (const float*)d_in[6];
    const float* g2  = (const float*)d_in[7];
    const float* be2 = (const float*)d_in[8];
    float* outf = (float*)d_out;

    char* ws = (char*)d_ws;
    _Float16* wp1   = (_Float16*)ws;                       // 9216 halves
    _Float16* wp2   = wp1 + 9216;                          // 9216 halves -> 36864 B
    float* partials = (float*)(ws + 36864);                // [64][1024] floats = 256 KB
    float* scsh1    = (float*)(ws + 36864 + 262144);       // 64
    float* scsh2    = scsh1 + 64;                          // 64
    _Float16* bufA  = (_Float16*)(scsh2 + 64);             // 32 MB: t0c, later t4c
    _Float16* bufB  = bufA + (size_t)NLOC*CH;              // 32 MB: t1c

    wprep_kernel<<<72, 256, 0, stream>>>(w1, w2, wp1, wp2);
    pre_kernel<<<dim3(HWDIM, NB), 256, 0, stream>>>(x, bufA);                   // t0c = logmap0(x)

    conv_mfma_kernel<1><<<GRIDC, 256, 0, stream>>>(bufA, wp1, b1, scsh1, bufB, partials);
    finalize_kernel<<<32, 256, 0, stream>>>(partials, g1, be1, scsh1);
    conv_mfma_kernel<2><<<GRIDC, 256, 0, stream>>>(bufB, wp2, b2, scsh1, bufA, partials);
    finalize_kernel<<<32, 256, 0, stream>>>(partials, g2, be2, scsh2);
    out_kernel<<<dim3(HWDIM, NB), 256, 0, stream>>>(bufA, scsh2, outf);
}

// Round 6
// 202.897 us; speedup vs baseline: 1.5701x; 1.0103x over previous
//
#include <hip/hip_runtime.h>
#include <math.h>

#define HWDIM 256
#define CH 32
#define NB 8
#define TILE 16
#define NLOC (NB*HWDIM*HWDIM)   /* 524288 locations */
#define R_CLAMP 4.9517189f      /* artanh(0.9999) */
#define MAXN 0.9999f
#define BN_EPS 1e-5f
#define EPSF 1e-5f
#define TPB 2                   /* tiles per conv block */
#define GRIDC 1024              /* conv blocks = 2048 tiles / TPB; 4 per CU */
#define OST 264                 /* out_kernel LDS row stride (floats) */

typedef __attribute__((ext_vector_type(8))) _Float16 half8;
typedef __attribute__((ext_vector_type(4))) _Float16 half4;
typedef __attribute__((ext_vector_type(4))) float floatx4;

__device__ __forceinline__ float artanh_fast(float n) {
    float t = fminf(n, 1.0f - 1e-5f);
    // artanh(t) = 0.5*ln((1+t)/(1-t)); one v_log + fast divide; ~1e-6 rel err << fp16 path
    return 0.5f * __logf(__fdividef(1.0f + t, 1.0f - t));
}

// pack both weight tensors to fp16: w[co][ci][3][3] -> wp[((o*4+g)*32+co)*8+j], ci=g*8+j
__global__ __launch_bounds__(256) void wprep_kernel(
    const float* __restrict__ w1, const float* __restrict__ w2,
    _Float16* __restrict__ wp1, _Float16* __restrict__ wp2)
{
    int idx = blockIdx.x * 256 + threadIdx.x;
    if (idx >= 2*CH*CH*9) return;
    int s = idx >= CH*CH*9;
    int id = idx - s*(CH*CH*9);
    const float* w = s ? w2 : w1;
    _Float16* wp = s ? wp2 : wp1;
    int j  = id & 7;
    int r  = id >> 3;
    int co = r & 31;
    int og = r >> 5;
    int g  = og & 3;
    int o  = og >> 2;
    int ci = g*8 + j;
    wp[id] = (_Float16)w[(co*CH + ci)*9 + o];
}

// transform one halo loc -> fp16 A-tile row in LDS (layout [18y][4g][18x][8ci])
// STAGE 1: src = x fp32 NCHW, apply logmap0 (transient v[32]; round-0-proven no-spill).
// STAGE 2: src = t1 fp16 channel-minor, apply bn1 + clampnorm + relu.
template<int STAGE>
__device__ __forceinline__ void stage_loc(const void* __restrict__ srcv, int bz,
                                          int gh, int gw, bool inb,
                                          _Float16* base, const float* __restrict__ scsh)
{
    if (!inb) {
        half8 z = {0,0,0,0,0,0,0,0};
        #pragma unroll
        for (int g = 0; g < 4; g++) *(half8*)(base + g*144) = z;
        return;
    }
    float v[CH]; float n2 = 0.f;
    if (STAGE == 1) {
        const float* p = (const float*)srcv + ((size_t)bz*CH << 16) + gh*HWDIM + gw;
        #pragma unroll
        for (int c = 0; c < CH; c++) { float t0 = p[(size_t)c << 16]; v[c] = t0; n2 = fmaf(t0, t0, n2); }
        float n = fmaxf(sqrtf(n2), EPSF);
        float f = __fdividef(artanh_fast(n), n);
        #pragma unroll
        for (int g = 0; g < 4; g++) {
            half8 hv;
            #pragma unroll
            for (int j = 0; j < 8; j++) hv[j] = (_Float16)(v[g*8 + j] * f);
            *(half8*)(base + g*144) = hv;
        }
    } else {
        const _Float16* p = (const _Float16*)srcv + (((size_t)bz << 16) + gh*HWDIM + gw)*CH;
        half8 raw[4];
        #pragma unroll
        for (int k = 0; k < 4; k++) raw[k] = *(const half8*)(p + 8*k);
        #pragma unroll
        for (int c = 0; c < CH; c++) {
            float t0 = fmaf((float)raw[c>>3][c&7], scsh[c], scsh[CH + c]);
            v[c] = t0; n2 = fmaf(t0, t0, n2);
        }
        float n = sqrtf(n2);
        float f = (n > R_CLAMP) ? __fdividef(R_CLAMP, n) : 1.0f;
        #pragma unroll
        for (int g = 0; g < 4; g++) {
            half8 hv;
            #pragma unroll
            for (int j = 0; j < 8; j++) hv[j] = (_Float16)fmaxf(v[g*8 + j]*f, 0.0f);
            *(half8*)(base + g*144) = hv;
        }
    }
}

// Multi-tile conv: TPB tiles marching in x per block (1024 blocks, 4/CU, all resident;
// blocks drift out of phase across tiles -> inter-block latency hiding).
// No staging state lives across the MFMA phase (rounds 1-3 spill lesson).
template<int STAGE>
__global__ __launch_bounds__(256) void conv_mfma_kernel(
    const void* __restrict__ srcv,        // STAGE1: fp32 NCHW x; STAGE2: fp16 ch-minor t1
    const _Float16* __restrict__ wp,      // [9][4][32co][8ci] fp16
    const float* __restrict__ bias,
    const float* __restrict__ scsh,       // [2*CH] (STAGE 2)
    _Float16* __restrict__ dst,
    float* __restrict__ partials)         // [64][GRIDC] transposed
{
    __shared__ _Float16 ah[10368];        // [18y][4g][18x][8ci] = 20736 B
    __shared__ float red[4][64];

    const int tid = threadIdx.x;
    const int b   = blockIdx.x;           // 0..1023
    const int bz  = b & 7;                // image per XCD
    const int tb  = b >> 3;               // 0..127
    const int by  = tb >> 3;              // 0..15
    const int bx0 = (tb & 7) * TPB;       // 0,2,..,14
    const int h0  = by*TILE - 1;
    const int wbase = bx0*TILE - 1;

    // staging locs: loc0 = tid (all threads), loc1 = tid+256 (tid<68)
    const int sy0 = tid / 18, sx0 = tid - sy0*18;
    const int gh0 = h0 + sy0;
    const bool row0 = (gh0 >= 0) & (gh0 < HWDIM);
    const bool has1 = tid < 68;
    const int l1 = tid + 256;
    const int sy1 = l1 / 18, sx1 = l1 - sy1*18;
    const int gh1 = h0 + sy1;
    const bool row1 = has1 & (gh1 >= 0) & (gh1 < HWDIM);
    _Float16* const base0 = ah + ((sy0*4)*18 + sx0)*8;
    _Float16* const base1 = ah + ((sy1*4)*18 + sx1)*8;

    const int lane = tid & 63, wave = tid >> 6;
    const int xx = lane & 15, q = lane >> 4;

    float bs[8];
    #pragma unroll
    for (int r = 0; r < 4; r++) { bs[r] = bias[q*4+r]; bs[4+r] = bias[q*4+r+16]; }
    float sv[8], qv[8];
    #pragma unroll
    for (int k = 0; k < 8; k++) { sv[k] = 0.f; qv[k] = 0.f; }

    #pragma unroll 1
    for (int j = 0; j < TPB; j++) {
        // ---- staging: per-loc load+transform+LDS-store, regs transient ----
        {
            int gw0 = wbase + j*TILE + sx0;
            bool in0 = row0 & (gw0 >= 0) & (gw0 < HWDIM);
            stage_loc<STAGE>(srcv, bz, gh0, gw0, in0, base0, scsh);
        }
        if (has1) {
            int gw1 = wbase + j*TILE + sx1;
            bool in1 = row1 & (gw1 >= 0) & (gw1 < HWDIM);
            stage_loc<STAGE>(srcv, bz, gh1, gw1, in1, base1, scsh);
        }
        __syncthreads();

        // ---- implicit GEMM, swapped operands: A = weights (m=co), B = acts (n=loc) ----
        floatx4 acc[4][2];
        #pragma unroll
        for (int i = 0; i < 4; i++) {
            acc[i][0] = (floatx4){0.f,0.f,0.f,0.f};
            acc[i][1] = (floatx4){0.f,0.f,0.f,0.f};
        }
        __builtin_amdgcn_s_setprio(1);
        #pragma unroll
        for (int dx = 0; dx < 3; dx++) {
            half8 af[6];
            #pragma unroll
            for (int yy = 0; yy < 6; yy++)
                af[yy] = *(const half8*)(ah + (((wave*4+yy)*4 + q)*18 + xx + dx)*8);
            #pragma unroll
            for (int dy = 0; dy < 3; dy++) {
                const int o = dy*3 + dx;
                const _Float16* wb = wp + (size_t)((o*4 + q)*32)*8;
                half8 wf0 = *(const half8*)(wb + xx*8);          // co 0..15
                half8 wf1 = *(const half8*)(wb + (xx+16)*8);     // co 16..31
                #pragma unroll
                for (int i = 0; i < 4; i++) {
                    acc[i][0] = __builtin_amdgcn_mfma_f32_16x16x32_f16(wf0, af[i+dy], acc[i][0], 0,0,0);
                    acc[i][1] = __builtin_amdgcn_mfma_f32_16x16x32_f16(wf1, af[i+dy], acc[i][1], 0,0,0);
                }
            }
        }
        __builtin_amdgcn_s_setprio(0);

        // ---- register epilogue: thread owns ch {q*4+r, q*4+r+16} of loc (y=wave*4+i, x=xx) ----
        _Float16* dp = dst + (((size_t)bz << 16) + (size_t)(by*TILE)*HWDIM + (bx0 + j)*TILE + xx)*CH + q*4;
        #pragma unroll
        for (int i = 0; i < 4; i++) {
            float n2 = 0.f;
            #pragma unroll
            for (int r = 0; r < 4; r++) {
                acc[i][0][r] += bs[r];
                acc[i][1][r] += bs[4+r];
                n2 = fmaf(acc[i][0][r], acc[i][0][r], n2);
                n2 = fmaf(acc[i][1][r], acc[i][1][r], n2);
            }
            n2 += __shfl_xor(n2, 16, 64);
            n2 += __shfl_xor(n2, 32, 64);
            float nn = sqrtf(n2);
            float f = (nn > R_CLAMP) ? __fdividef(R_CLAMP, nn) : 1.0f;
            half4 o0, o1;
            #pragma unroll
            for (int r = 0; r < 4; r++) {
                float a0 = acc[i][0][r] * f;
                float a1 = acc[i][1][r] * f;
                sv[r]   += a0; qv[r]   = fmaf(a0, a0, qv[r]);
                sv[4+r] += a1; qv[4+r] = fmaf(a1, a1, qv[4+r]);
                o0[r] = (_Float16)a0; o1[r] = (_Float16)a1;
            }
            _Float16* a = dp + (size_t)(wave*4 + i)*HWDIM*CH;
            *(half4*)(a)      = o0;
            *(half4*)(a + 16) = o1;
        }
        __syncthreads();                   // LDS safe to overwrite next iteration
    }

    // BN partials accumulated over TPB tiles, reduced once per block
    #pragma unroll
    for (int k = 0; k < 8; k++) {
        #pragma unroll
        for (int m = 1; m < 16; m <<= 1) {
            sv[k] += __shfl_xor(sv[k], m, 64);
            qv[k] += __shfl_xor(qv[k], m, 64);
        }
    }
    if (xx == 0) {
        #pragma unroll
        for (int r = 0; r < 4; r++) {
            red[wave][q*4+r]        = sv[r];
            red[wave][16 + q*4+r]   = sv[4+r];
            red[wave][32 + q*4+r]   = qv[r];
            red[wave][48 + q*4+r]   = qv[4+r];
        }
    }
    __syncthreads();
    if (tid < 64) {
        float s = red[0][tid] + red[1][tid] + red[2][tid] + red[3][tid];
        partials[(size_t)tid*GRIDC + b] = s;
    }
}

__global__ __launch_bounds__(256) void finalize_kernel(
    const float* __restrict__ partials,
    const float* __restrict__ g, const float* __restrict__ beta,
    float* __restrict__ scsh)
{
    __shared__ float ss[256], sq[256];
    const int c = blockIdx.x;
    const int tid = threadIdx.x;
    float s = 0.f, q = 0.f;
    for (int b = tid; b < GRIDC; b += 256) {
        s += partials[(size_t)c*GRIDC + b];
        q += partials[(size_t)(CH + c)*GRIDC + b];
    }
    ss[tid] = s; sq[tid] = q;
    __syncthreads();
    for (int st = 128; st > 0; st >>= 1) {
        if (tid < st) { ss[tid] += ss[tid+st]; sq[tid] += sq[tid+st]; }
        __syncthreads();
    }
    if (tid == 0) {
        const float NS = (float)NLOC;
        float mean = ss[0] / NS;
        float var = fmaxf(sq[0] / NS - mean*mean, 0.0f);
        float sc = g[c] / sqrtf(var + BN_EPS);
        scsh[c] = sc;
        scsh[CH + c] = beta[c] - mean*sc;
    }
}

// read t4 fp16 channel-minor; bn2+clampnorm+relu+expmap0+project; write fp32 NCHW
__global__ __launch_bounds__(256) void out_kernel(
    const _Float16* __restrict__ t4c, const float* __restrict__ scsh,
    float* __restrict__ out)
{
    __shared__ float outb[16*OST];
    const int w = threadIdx.x;
    const int h = blockIdx.x, n = blockIdx.y;
    const _Float16* p = t4c + (((size_t)n << 16) + (size_t)h*HWDIM + w)*CH;
    half8 raw[4];
    #pragma unroll
    for (int k = 0; k < 4; k++) raw[k] = *(const half8*)(p + 8*k);
    float u[CH]; float n2 = 0.f;
    #pragma unroll
    for (int c = 0; c < CH; c++) {
        float t = fmaf((float)raw[c>>3][c&7], scsh[c], scsh[CH+c]);
        u[c] = t; n2 = fmaf(t, t, n2);
    }
    float nn = sqrtf(n2);
    float f = (nn > R_CLAMP) ? __fdividef(R_CLAMP, nn) : 1.0f;
    float r2 = 0.f;
    #pragma unroll
    for (int c = 0; c < CH; c++) { float r = fmaxf(u[c]*f, 0.0f); u[c] = r; r2 = fmaf(r, r, r2); }
    float rn = fmaxf(sqrtf(r2), EPSF);
    // tanh(rn) = (e^{2rn}-1)/(e^{2rn}+1); rn <= ~4.95 so e^{2rn} <= ~2e4, safe in fp32
    float a = __expf(2.0f * rn);
    float th = __fdividef(a - 1.0f, a + 1.0f);
    float s = __fdividef(fminf(th, MAXN), rn);
    #pragma unroll
    for (int c = 0; c < CH; c++) u[c] *= s;

    #pragma unroll
    for (int hf = 0; hf < 2; hf++) {
        if (hf) __syncthreads();
        #pragma unroll
        for (int c = 0; c < 16; c++) outb[c*OST + w] = u[hf*16 + c];
        __syncthreads();
        int co = threadIdx.x >> 4, seg = threadIdx.x & 15;
        const float* row = outb + co*OST + seg*16;
        float* gp = out + ((size_t)(n*CH + hf*16 + co) << 16) + (size_t)h*HWDIM + seg*16;
        #pragma unroll
        for (int k = 0; k < 4; k++) *(floatx4*)(gp + 4*k) = *(const floatx4*)(row + 4*k);
    }
}

extern "C" void kernel_launch(void* const* d_in, const int* in_sizes, int n_in,
                              void* d_out, int out_size, void* d_ws, size_t ws_size,
                              hipStream_t stream)
{
    const float* x   = (const float*)d_in[0];
    const float* w1  = (const float*)d_in[1];
    const float* b1  = (const float*)d_in[2];
    const float* g1  = (const float*)d_in[3];
    const float* be1 = (const float*)d_in[4];
    const float* w2  = (const float*)d_in[5];
    const float* b2  = (const float*)d_in[6];
    const float* g2  = (const float*)d_in[7];
    const float* be2 = (const float*)d_in[8];
    float* outf = (float*)d_out;

    char* ws = (char*)d_ws;
    _Float16* wp1   = (_Float16*)ws;                       // 9216 halves
    _Float16* wp2   = wp1 + 9216;                          // 9216 halves -> 36864 B
    float* partials = (float*)(ws + 36864);                // [64][1024] floats = 256 KB
    float* scsh1    = (float*)(ws + 36864 + 262144);       // 64
    float* scsh2    = scsh1 + 64;                          // 64
    _Float16* t1c   = (_Float16*)(scsh2 + 64);             // 32 MB
    _Float16* t4c   = t1c + (size_t)NLOC*CH;               // 32 MB

    wprep_kernel<<<72, 256, 0, stream>>>(w1, w2, wp1, wp2);

    conv_mfma_kernel<1><<<GRIDC, 256, 0, stream>>>(x, wp1, b1, scsh1, t1c, partials);
    finalize_kernel<<<32, 256, 0, stream>>>(partials, g1, be1, scsh1);
    conv_mfma_kernel<2><<<GRIDC, 256, 0, stream>>>(t1c, wp2, b2, scsh1, t4c, partials);
    finalize_kernel<<<32, 256, 0, stream>>>(partials, g2, be2, scsh2);
    out_kernel<<<dim3(HWDIM, NB), 256, 0, stream>>>(t4c, scsh2, outf);
}